// Round 8
// baseline (223.392 us; speedup 1.0000x reference)
//
#include <hip/hip_runtime.h>
#include <cstdint>
#include <cstddef>

#define NN 1024
#define BB 4
#define CC 256
#define HH 4
#define DD 64
#define EE 32768
#define ROWS 8
#define CAP 128
#define NTHR 256

struct Params {
    const float *x, *ef;
    const int *src, *trg;
    const float *Wn1, *We1, *as1, *at1, *ae1;
    const float *Wn2, *We2, *as2, *at2, *ae2;
    float *out;
    float *WnT1, *WnT2, *wsum, *pe, *hbuf, *alphas, *alphat;
    float *hbuf2, *alphas2, *alphat2;
    int *cnt, *flag, *bucket;
};

// ---------------- proj: rows r0..r0+7 of (x @ Wn.T); x via wave-uniform scalar loads ----------------
__device__ __forceinline__ void proj_body(const float* __restrict__ x,
                                          const float* __restrict__ WT,
                                          const float* __restrict__ a_s,
                                          const float* __restrict__ a_t,
                                          float* __restrict__ hout,
                                          float* __restrict__ alpha_s,
                                          float* __restrict__ alpha_t,
                                          int bid, int t) {
    int r0 = bid * ROWS;
    const float* xr = x + (size_t)r0 * CC;
    float acc[ROWS];
#pragma unroll
    for (int j = 0; j < ROWS; ++j) acc[j] = 0.f;
#pragma unroll 4
    for (int c = 0; c < CC; ++c) {
        float w = WT[c * CC + t];
#pragma unroll
        for (int j = 0; j < ROWS; ++j) acc[j] += w * xr[(size_t)j * CC + c];
    }
    int h = t >> 6, d = t & 63;
    float as = a_s[h * DD + d], at = a_t[h * DD + d];
#pragma unroll
    for (int j = 0; j < ROWS; ++j) {
        hout[(size_t)(r0 + j) * CC + t] = acc[j];
        float vs = acc[j] * as, vt = acc[j] * at;
#pragma unroll
        for (int off = 32; off; off >>= 1) {
            vs += __shfl_down(vs, off, 64);
            vt += __shfl_down(vt, off, 64);
        }
        if (d == 0) {
            alpha_s[(size_t)(r0 + j) * HH + h] = vs;
            alpha_t[(size_t)(r0 + j) * HH + h] = vt;
        }
    }
}

// rank-sort node n's bucket (deg<=64 wave-parallel; else serial) into sed[]
__device__ __forceinline__ void sort_bucket(const Params& p, int n, int deg, int lane,
                                            int* sed) {
    if (deg <= 64) {
        int v = (lane < deg) ? p.bucket[n * CAP + lane] : 0x7fffffff;
        int rank = 0;
#pragma unroll
        for (int j = 0; j < 64; ++j) {
            int vj = __shfl(v, j, 64);
            rank += (vj < v) ? 1 : 0;
        }
        if (lane < deg) sed[rank] = v;
    } else if (lane == 0) {
        for (int i = 0; i < deg; ++i) sed[i] = p.bucket[n * CAP + i];
        for (int i = 1; i < deg; ++i) {
            int v = sed[i], j = i - 1;
            while (j >= 0 && sed[j] > v) { sed[j + 1] = sed[j]; --j; }
            sed[j + 1] = v;
        }
    }
}

// ---------------- K1: transposes + wsum + zero(cnt,flag) ----------------
__global__ __launch_bounds__(NTHR) void k_prep(Params p) {
    __shared__ float tile[64][65];
    int bid = blockIdx.x, t = threadIdx.x;
    if (bid < 32) {
        int m = bid >> 4, tl = bid & 15, ti = tl >> 2, tj = tl & 3;
        const float* W = m ? p.Wn2 : p.Wn1;
        float* WT = m ? p.WnT2 : p.WnT1;
#pragma unroll
        for (int k = 0; k < 16; ++k) {
            int idx = k * 256 + t, r = idx >> 6, c = idx & 63;
            tile[r][c] = W[(ti * 64 + r) * CC + tj * 64 + c];
        }
        __syncthreads();
#pragma unroll
        for (int k = 0; k < 16; ++k) {
            int idx = k * 256 + t, r = idx >> 6, c = idx & 63;
            WT[(tj * 64 + r) * CC + ti * 64 + c] = tile[c][r];
        }
    } else if (bid < 40) {
        int idx = (bid - 32) * 256 + t;
        int l = idx >> 10, h = (idx >> 8) & 3, c = idx & 255;
        const float* We = l ? p.We2 : p.We1;
        const float* ae = l ? p.ae2 : p.ae1;
        float s = 0.f;
        for (int d = 0; d < DD; ++d) s += We[(h * DD + d) * CC + c];
        p.wsum[(l * HH + h) * CC + c] = s * ae[h];
    } else {
#pragma unroll
        for (int k = 0; k < 4; ++k) {
            p.cnt[k * 256 + t] = 0;
            p.flag[k * 256 + t] = 0;
        }
    }
}

// ---------------- K2: fill || proj1 || pe ----------------
__global__ __launch_bounds__(NTHR) void k_main1(Params p) {
    int bid = blockIdx.x, t = threadIdx.x;
    if (bid < 128) {
        int e = bid * NTHR + t;
        int n = p.trg[e];
        int pos = atomicAdd(&p.cnt[n], 1);
        if (pos < CAP) p.bucket[n * CAP + pos] = e;
    } else if (bid < 640) {
        proj_body(p.x, p.WnT1, p.as1, p.at1, p.hbuf, p.alphas, p.alphat, bid - 128, t);
    } else {
        int pb = bid - 640, wid = t >> 6, lane = t & 63;
        float4 wv[8];
#pragma unroll
        for (int i = 0; i < 8; ++i)
            wv[i] = *(const float4*)(p.wsum + i * CC + lane * 4);
#pragma unroll
        for (int k = 0; k < 4; ++k) {
            int e = pb * 16 + wid * 4 + k;
            int s = p.src[e], g = p.trg[e];
            float4 v = *(const float4*)(p.ef + ((long)s * NN + g) * CC + lane * 4);
            float acc[8];
#pragma unroll
            for (int i = 0; i < 8; ++i)
                acc[i] = v.x * wv[i].x + v.y * wv[i].y + v.z * wv[i].z + v.w * wv[i].w;
#pragma unroll
            for (int off = 32; off; off >>= 1)
#pragma unroll
                for (int i = 0; i < 8; ++i) acc[i] += __shfl_down(acc[i], off, 64);
            if (lane == 0) {
                *(float4*)(p.pe + (size_t)e * HH) =
                    make_float4(acc[0], acc[1], acc[2], acc[3]);
                *(float4*)(p.pe + (size_t)EE * HH + (size_t)e * HH) =
                    make_float4(acc[4], acc[5], acc[6], acc[7]);
            }
        }
    }
}

// ---------------- K3 mega: agg1+proj2 (producers) | agg2 (consumers) ----------------
// 1536 blocks, 6 blocks/CU forced -> all co-resident -> flag spin is deadlock-free.
__global__ __launch_bounds__(NTHR, 6) void k_mega(Params p) {
    __shared__ int sedge[2][CAP];
    __shared__ int ssrc[2][CAP];
    __shared__ float spe[2][CAP][HH];
    __shared__ float x1s[8][CC];
    __shared__ int sdeg[2];
    int bid = blockIdx.x, t = threadIdx.x, w = t >> 6, lane = t & 63;

    if (bid < 512) {
        // ---------- producer: agg layer1 for nodes 2b,2b+1 -> proj2 -> flags ----------
        int n0 = bid * 2;
        if (w < 2) {
            int n = n0 + w;
            int deg = p.cnt[n];
            if (deg > CAP) deg = CAP;
            if (lane == 0) sdeg[w] = deg;
            sort_bucket(p, n, deg, lane, sedge[w]);
        }
        __syncthreads();
        {
            int k = t >> 7, idx = t & 127;
            if (idx < sdeg[k]) {
                int e = sedge[k][idx];
                ssrc[k][idx] = p.src[e];
                *(float4*)spe[k][idx] = *(const float4*)(p.pe + (size_t)e * HH);
            }
        }
        __syncthreads();
        int h = lane >> 4;
        // agg layer 1: wave w = batch; k = node slot; x1 kept in LDS
#pragma unroll
        for (int k = 0; k < 2; ++k) {
            int n = n0 + k, deg = sdeg[k];
            float at_n = p.alphat[((size_t)n * BB + w) * HH + h];
            float ax = 0.f, ay = 0.f, az = 0.f, aw = 0.f, den = 0.f;
#pragma unroll 4
            for (int i = 0; i < deg; ++i) {
                int s = ssrc[k][i];
                float sc = p.alphas[((size_t)s * BB + w) * HH + h] + at_n + spe[k][i][h];
                sc = sc > 0.f ? sc : 0.2f * sc;
                float ex = __expf(sc);
                float4 v = *(const float4*)(p.hbuf + ((size_t)s * BB + w) * CC + lane * 4);
                ax += ex * v.x; ay += ex * v.y; az += ex * v.z; aw += ex * v.w;
                den += ex;
            }
            float inv = 1.f / (den + 1e-16f);
            *(float4*)&x1s[(k << 2) | w][lane * 4] =
                make_float4(ax * inv, ay * inv, az * inv, aw * inv);
        }
        __syncthreads();
        // proj2 on the 8 LDS rows
        float acc[8];
#pragma unroll
        for (int r = 0; r < 8; ++r) acc[r] = 0.f;
#pragma unroll 4
        for (int c = 0; c < CC; ++c) {
            float wv = p.WnT2[c * CC + t];
#pragma unroll
            for (int r = 0; r < 8; ++r) acc[r] += wv * x1s[r][c];
        }
        int hh = t >> 6, d = t & 63;
        float as = p.as2[hh * DD + d], at = p.at2[hh * DD + d];
#pragma unroll
        for (int r = 0; r < 8; ++r) {
            int n = n0 + (r >> 2), b = r & 3;
            p.hbuf2[((size_t)n * BB + b) * CC + t] = acc[r];
            float vs = acc[r] * as, vt = acc[r] * at;
#pragma unroll
            for (int off = 32; off; off >>= 1) {
                vs += __shfl_down(vs, off, 64);
                vt += __shfl_down(vt, off, 64);
            }
            if (d == 0) {
                p.alphas2[((size_t)n * BB + b) * HH + hh] = vs;
                p.alphat2[((size_t)n * BB + b) * HH + hh] = vt;
            }
        }
        __syncthreads();
        if (t < 2) {
            __threadfence();  // make hbuf2/alphas2/alphat2 visible device-wide
            __hip_atomic_store(&p.flag[n0 + t], 1, __ATOMIC_RELEASE,
                               __HIP_MEMORY_SCOPE_AGENT);
        }
    } else {
        // ---------- consumer: agg layer 2 for node n ----------
        int n = bid - 512;
        if (w == 0) {
            int deg = p.cnt[n];
            if (deg > CAP) deg = CAP;
            if (lane == 0) sdeg[0] = deg;
            sort_bucket(p, n, deg, lane, sedge[0]);
        }
        __syncthreads();
        int deg = sdeg[0];
        if (t < deg) {
            int e = sedge[0][t];
            ssrc[0][t] = p.src[e];
            *(float4*)spe[0][t] = *(const float4*)(p.pe + (size_t)EE * HH + (size_t)e * HH);
        }
        // spin until all needed producer flags are set (co-residency guarantees progress)
        if (t < deg) {
            int s = ssrc[0][t];
            while (__hip_atomic_load(&p.flag[s], __ATOMIC_RELAXED,
                                     __HIP_MEMORY_SCOPE_AGENT) == 0)
                __builtin_amdgcn_s_sleep(2);
        }
        if (t == 255) {
            while (__hip_atomic_load(&p.flag[n], __ATOMIC_RELAXED,
                                     __HIP_MEMORY_SCOPE_AGENT) == 0)
                __builtin_amdgcn_s_sleep(2);
        }
        __syncthreads();
        __threadfence();  // acquire: invalidate stale cache lines before data reads
        int h = lane >> 4;
        float at_n = p.alphat2[((size_t)n * BB + w) * HH + h];
        float ax = 0.f, ay = 0.f, az = 0.f, aw = 0.f, den = 0.f;
#pragma unroll 4
        for (int i = 0; i < deg; ++i) {
            int s = ssrc[0][i];
            float sc = p.alphas2[((size_t)s * BB + w) * HH + h] + at_n + spe[0][i][h];
            sc = sc > 0.f ? sc : 0.2f * sc;
            float ex = __expf(sc);
            float4 v = *(const float4*)(p.hbuf2 + ((size_t)s * BB + w) * CC + lane * 4);
            ax += ex * v.x; ay += ex * v.y; az += ex * v.z; aw += ex * v.w;
            den += ex;
        }
        float inv = 1.f / (den + 1e-16f);
        *(float4*)(p.out + ((size_t)n * BB + w) * CC + lane * 4) =
            make_float4(ax * inv, ay * inv, az * inv, aw * inv);
    }
}

// ---------------- launch ----------------
extern "C" void kernel_launch(void* const* d_in, const int* in_sizes, int n_in,
                              void* d_out, int out_size, void* d_ws, size_t ws_size,
                              hipStream_t stream) {
    float* wsf = (float*)d_ws;
    Params p;
    p.x   = (const float*)d_in[0];
    p.ef  = (const float*)d_in[1];
    p.src = (const int*)d_in[2];
    p.trg = (const int*)d_in[3];
    p.Wn1 = (const float*)d_in[4];
    p.We1 = (const float*)d_in[5];
    p.as1 = (const float*)d_in[6];
    p.at1 = (const float*)d_in[7];
    p.ae1 = (const float*)d_in[8];
    p.Wn2 = (const float*)d_in[9];
    p.We2 = (const float*)d_in[10];
    p.as2 = (const float*)d_in[11];
    p.at2 = (const float*)d_in[12];
    p.ae2 = (const float*)d_in[13];
    p.out = (float*)d_out;
    p.WnT1    = wsf;                  // 65536
    p.WnT2    = wsf + 65536;          // 65536
    p.wsum    = wsf + 131072;         // 2048
    p.pe      = wsf + 133120;         // 262144
    p.hbuf    = wsf + 395264;         // 1048576
    p.alphas  = wsf + 1443840;        // 16384
    p.alphat  = wsf + 1460224;        // 16384
    p.hbuf2   = wsf + 1476608;        // 1048576
    p.alphas2 = wsf + 2525184;        // 16384
    p.alphat2 = wsf + 2541568;        // 16384
    p.cnt     = (int*)(wsf + 2557952);           // 1024
    p.flag    = (int*)(wsf + 2557952 + 1024);    // 1024
    p.bucket  = (int*)(wsf + 2557952 + 2048);    // 1024*128

    k_prep<<<41, NTHR, 0, stream>>>(p);
    k_main1<<<2688, NTHR, 0, stream>>>(p);
    k_mega<<<1536, NTHR, 0, stream>>>(p);
}

// Round 9
// 108.509 us; speedup vs baseline: 2.0587x; 2.0587x over previous
//
#include <hip/hip_runtime.h>
#include <cstdint>
#include <cstddef>

#define NN 1024
#define BB 4
#define CC 256
#define HH 4
#define DD 64
#define EE 32768
#define ROWS 8
#define CAP 128
#define NTHR 256

struct Params {
    const float *x, *ef;
    const int *src, *trg;
    const float *Wn1, *We1, *as1, *at1, *ae1;
    const float *Wn2, *We2, *as2, *at2, *ae2;
    float *out;
    float *WnT1, *WnT2, *wsum, *pe, *hbuf, *alphas, *alphat;
    float *hbuf2, *alphas2, *alphat2;
    int *cnt, *bucket;
};

// ---------------- proj: rows r0..r0+7 of (x @ Wn.T); x via wave-uniform scalar loads ----------------
__device__ __forceinline__ void proj_body(const float* __restrict__ x,
                                          const float* __restrict__ WT,
                                          const float* __restrict__ a_s,
                                          const float* __restrict__ a_t,
                                          float* __restrict__ hout,
                                          float* __restrict__ alpha_s,
                                          float* __restrict__ alpha_t,
                                          int bid, int t) {
    int r0 = bid * ROWS;
    const float* xr = x + (size_t)r0 * CC;
    float acc[ROWS];
#pragma unroll
    for (int j = 0; j < ROWS; ++j) acc[j] = 0.f;
#pragma unroll 4
    for (int c = 0; c < CC; ++c) {
        float w = WT[c * CC + t];
#pragma unroll
        for (int j = 0; j < ROWS; ++j) acc[j] += w * xr[(size_t)j * CC + c];
    }
    int h = t >> 6, d = t & 63;
    float as = a_s[h * DD + d], at = a_t[h * DD + d];
#pragma unroll
    for (int j = 0; j < ROWS; ++j) {
        hout[(size_t)(r0 + j) * CC + t] = acc[j];
        float vs = acc[j] * as, vt = acc[j] * at;
#pragma unroll
        for (int off = 32; off; off >>= 1) {
            vs += __shfl_down(vs, off, 64);
            vt += __shfl_down(vt, off, 64);
        }
        if (d == 0) {
            alpha_s[(size_t)(r0 + j) * HH + h] = vs;
            alpha_t[(size_t)(r0 + j) * HH + h] = vt;
        }
    }
}

// rank-sort node n's bucket (deg<=64 wave-parallel; else serial) into sed[]
__device__ __forceinline__ void sort_bucket(const Params& p, int n, int deg, int lane,
                                            int* sed) {
    if (deg <= 64) {
        int v = (lane < deg) ? p.bucket[n * CAP + lane] : 0x7fffffff;
        int rank = 0;
#pragma unroll
        for (int j = 0; j < 64; ++j) {
            int vj = __shfl(v, j, 64);
            rank += (vj < v) ? 1 : 0;
        }
        if (lane < deg) sed[rank] = v;
    } else if (lane == 0) {
        for (int i = 0; i < deg; ++i) sed[i] = p.bucket[n * CAP + i];
        for (int i = 1; i < deg; ++i) {
            int v = sed[i], j = i - 1;
            while (j >= 0 && sed[j] > v) { sed[j + 1] = sed[j]; --j; }
            sed[j + 1] = v;
        }
    }
}

// stage sorted edges: src ids, pe rows, alphas rows (16 contiguous floats per node)
__device__ __forceinline__ void stage_edges(const Params& p, const float* __restrict__ pe_l,
                                            const float* __restrict__ als, int t, int deg,
                                            const int* sed, int* ssrc,
                                            float (*spe)[HH], float (*sals)[16]) {
    if (t < deg) {
        int e = sed[t];
        int s = p.src[e];
        ssrc[t] = s;
        *(float4*)spe[t] = *(const float4*)(pe_l + (size_t)e * HH);
        const float4* ap = (const float4*)(als + (size_t)s * 16);
        float4* dp = (float4*)sals[t];
        dp[0] = ap[0]; dp[1] = ap[1]; dp[2] = ap[2]; dp[3] = ap[3];
    }
}

// ---------------- K1: transposes + wsum + cnt zero ----------------
__global__ __launch_bounds__(NTHR) void k_prep(Params p) {
    __shared__ float tile[64][65];
    int bid = blockIdx.x, t = threadIdx.x;
    if (bid < 32) {
        int m = bid >> 4, tl = bid & 15, ti = tl >> 2, tj = tl & 3;
        const float* W = m ? p.Wn2 : p.Wn1;
        float* WT = m ? p.WnT2 : p.WnT1;
#pragma unroll
        for (int k = 0; k < 16; ++k) {
            int idx = k * 256 + t, r = idx >> 6, c = idx & 63;
            tile[r][c] = W[(ti * 64 + r) * CC + tj * 64 + c];
        }
        __syncthreads();
#pragma unroll
        for (int k = 0; k < 16; ++k) {
            int idx = k * 256 + t, r = idx >> 6, c = idx & 63;
            WT[(tj * 64 + r) * CC + ti * 64 + c] = tile[c][r];
        }
    } else if (bid < 40) {
        int idx = (bid - 32) * 256 + t;
        int l = idx >> 10, h = (idx >> 8) & 3, c = idx & 255;
        const float* We = l ? p.We2 : p.We1;
        const float* ae = l ? p.ae2 : p.ae1;
        float s = 0.f;
        for (int d = 0; d < DD; ++d) s += We[(h * DD + d) * CC + c];
        p.wsum[(l * HH + h) * CC + c] = s * ae[h];
    } else {
        p.cnt[(bid - 40) * 256 + t] = 0;
    }
}

// ---------------- K2: fill || proj1 || pe ----------------
// bid 0..127: bucket fill ; 128..639: proj1 ; 640..2687: pe (16 edges/block, 4/wave)
__global__ __launch_bounds__(NTHR) void k_main1(Params p) {
    int bid = blockIdx.x, t = threadIdx.x;
    if (bid < 128) {
        int e = bid * NTHR + t;
        int n = p.trg[e];
        int pos = atomicAdd(&p.cnt[n], 1);
        if (pos < CAP) p.bucket[n * CAP + pos] = e;
    } else if (bid < 640) {
        proj_body(p.x, p.WnT1, p.as1, p.at1, p.hbuf, p.alphas, p.alphat, bid - 128, t);
    } else {
        int pb = bid - 640, wid = t >> 6, lane = t & 63;
        float4 wv[8];
#pragma unroll
        for (int i = 0; i < 8; ++i)
            wv[i] = *(const float4*)(p.wsum + i * CC + lane * 4);
        int e0 = pb * 16 + wid * 4;
        int4 s4 = *(const int4*)(p.src + e0);
        int4 g4 = *(const int4*)(p.trg + e0);
        int se[4] = {s4.x, s4.y, s4.z, s4.w};
        int ge[4] = {g4.x, g4.y, g4.z, g4.w};
        // issue all 4 row gathers first (memory-level parallelism)
        float4 v[4];
#pragma unroll
        for (int k = 0; k < 4; ++k)
            v[k] = *(const float4*)(p.ef + ((long)se[k] * NN + ge[k]) * CC + lane * 4);
#pragma unroll
        for (int k = 0; k < 4; ++k) {
            float acc[8];
#pragma unroll
            for (int i = 0; i < 8; ++i)
                acc[i] = v[k].x * wv[i].x + v[k].y * wv[i].y + v[k].z * wv[i].z
                       + v[k].w * wv[i].w;
#pragma unroll
            for (int off = 32; off; off >>= 1)
#pragma unroll
                for (int i = 0; i < 8; ++i) acc[i] += __shfl_down(acc[i], off, 64);
            if (lane == 0) {
                int e = e0 + k;
                *(float4*)(p.pe + (size_t)e * HH) =
                    make_float4(acc[0], acc[1], acc[2], acc[3]);
                *(float4*)(p.pe + (size_t)EE * HH + (size_t)e * HH) =
                    make_float4(acc[4], acc[5], acc[6], acc[7]);
            }
        }
    }
}

// ---------------- K3: fused agg1 + proj2 ; block = node, wave = batch ----------------
__global__ __launch_bounds__(NTHR) void k_fuse1(Params p) {
    __shared__ int sedge[CAP];
    __shared__ int ssrc[CAP];
    __shared__ float spe[CAP][HH];
    __shared__ float sals[CAP][16];
    __shared__ float x1s[4][CC];
    __shared__ int sdeg;
    int n = blockIdx.x, t = threadIdx.x, b = t >> 6, lane = t & 63;
    int deg = p.cnt[n];
    if (deg > CAP) deg = CAP;
    if (b == 0) {
        if (lane == 0) sdeg = deg;
        sort_bucket(p, n, deg, lane, sedge);
    }
    __syncthreads();
    stage_edges(p, p.pe, p.alphas, t, deg, sedge, ssrc, spe, sals);
    __syncthreads();

    // agg layer 1 -> x1 row (node n, batch b) in LDS
    int h = lane >> 4;
    float at_n = p.alphat[(size_t)n * 16 + b * 4 + h];
    float ax = 0.f, ay = 0.f, az = 0.f, aw = 0.f, den = 0.f;
#pragma unroll 4
    for (int i = 0; i < deg; ++i) {
        int s = ssrc[i];
        float sc = sals[i][b * 4 + h] + at_n + spe[i][h];
        sc = sc > 0.f ? sc : 0.2f * sc;
        float ex = __expf(sc);
        float4 v = *(const float4*)(p.hbuf + ((size_t)s * BB + b) * CC + lane * 4);
        ax += ex * v.x; ay += ex * v.y; az += ex * v.z; aw += ex * v.w;
        den += ex;
    }
    float inv = 1.f / (den + 1e-16f);
    *(float4*)&x1s[b][lane * 4] = make_float4(ax * inv, ay * inv, az * inv, aw * inv);
    __syncthreads();

    // proj2 on the 4 LDS rows of this node
    float acc[4];
#pragma unroll
    for (int r = 0; r < 4; ++r) acc[r] = 0.f;
#pragma unroll 4
    for (int c = 0; c < CC; ++c) {
        float w = p.WnT2[c * CC + t];
#pragma unroll
        for (int r = 0; r < 4; ++r) acc[r] += w * x1s[r][c];
    }
    int hh = t >> 6, d = t & 63;
    float as = p.as2[hh * DD + d], at = p.at2[hh * DD + d];
#pragma unroll
    for (int r = 0; r < 4; ++r) {
        p.hbuf2[((size_t)n * BB + r) * CC + t] = acc[r];
        float vs = acc[r] * as, vt = acc[r] * at;
#pragma unroll
        for (int off = 32; off; off >>= 1) {
            vs += __shfl_down(vs, off, 64);
            vt += __shfl_down(vt, off, 64);
        }
        if (d == 0) {
            p.alphas2[(size_t)n * 16 + r * 4 + hh] = vs;
            p.alphat2[(size_t)n * 16 + r * 4 + hh] = vt;
        }
    }
}

// ---------------- K4: agg layer 2 ; block = node, wave = batch ----------------
__global__ __launch_bounds__(NTHR) void k_agg2(Params p) {
    __shared__ int sedge[CAP];
    __shared__ int ssrc[CAP];
    __shared__ float spe[CAP][HH];
    __shared__ float sals[CAP][16];
    __shared__ int sdeg;
    int n = blockIdx.x, t = threadIdx.x, b = t >> 6, lane = t & 63;
    int deg = p.cnt[n];
    if (deg > CAP) deg = CAP;
    if (b == 0) {
        if (lane == 0) sdeg = deg;
        sort_bucket(p, n, deg, lane, sedge);
    }
    __syncthreads();
    stage_edges(p, p.pe + (size_t)EE * HH, p.alphas2, t, deg, sedge, ssrc, spe, sals);
    __syncthreads();

    int h = lane >> 4;
    float at_n = p.alphat2[(size_t)n * 16 + b * 4 + h];
    float ax = 0.f, ay = 0.f, az = 0.f, aw = 0.f, den = 0.f;
#pragma unroll 4
    for (int i = 0; i < deg; ++i) {
        int s = ssrc[i];
        float sc = sals[i][b * 4 + h] + at_n + spe[i][h];
        sc = sc > 0.f ? sc : 0.2f * sc;
        float ex = __expf(sc);
        float4 v = *(const float4*)(p.hbuf2 + ((size_t)s * BB + b) * CC + lane * 4);
        ax += ex * v.x; ay += ex * v.y; az += ex * v.z; aw += ex * v.w;
        den += ex;
    }
    float inv = 1.f / (den + 1e-16f);
    *(float4*)(p.out + ((size_t)n * BB + b) * CC + lane * 4) =
        make_float4(ax * inv, ay * inv, az * inv, aw * inv);
}

// ---------------- launch ----------------
extern "C" void kernel_launch(void* const* d_in, const int* in_sizes, int n_in,
                              void* d_out, int out_size, void* d_ws, size_t ws_size,
                              hipStream_t stream) {
    float* wsf = (float*)d_ws;
    Params p;
    p.x   = (const float*)d_in[0];
    p.ef  = (const float*)d_in[1];
    p.src = (const int*)d_in[2];
    p.trg = (const int*)d_in[3];
    p.Wn1 = (const float*)d_in[4];
    p.We1 = (const float*)d_in[5];
    p.as1 = (const float*)d_in[6];
    p.at1 = (const float*)d_in[7];
    p.ae1 = (const float*)d_in[8];
    p.Wn2 = (const float*)d_in[9];
    p.We2 = (const float*)d_in[10];
    p.as2 = (const float*)d_in[11];
    p.at2 = (const float*)d_in[12];
    p.ae2 = (const float*)d_in[13];
    p.out = (float*)d_out;
    p.WnT1    = wsf;                  // 65536
    p.WnT2    = wsf + 65536;          // 65536
    p.wsum    = wsf + 131072;         // 2048
    p.pe      = wsf + 133120;         // 262144
    p.hbuf    = wsf + 395264;         // 1048576
    p.alphas  = wsf + 1443840;        // 16384
    p.alphat  = wsf + 1460224;        // 16384
    p.hbuf2   = wsf + 1476608;        // 1048576
    p.alphas2 = wsf + 2525184;        // 16384
    p.alphat2 = wsf + 2541568;        // 16384
    p.cnt     = (int*)(wsf + 2557952);           // 1024
    p.bucket  = (int*)(wsf + 2557952 + 1024);    // 1024*128

    k_prep<<<44, NTHR, 0, stream>>>(p);
    k_main1<<<2688, NTHR, 0, stream>>>(p);
    k_fuse1<<<NN, NTHR, 0, stream>>>(p);
    k_agg2<<<NN, NTHR, 0, stream>>>(p);
}